// Round 3
// baseline (148.077 us; speedup 1.0000x reference)
//
#include <hip/hip_runtime.h>
#include <hip/hip_bf16.h>
#include <stdint.h>

#define NQ 10
#define DIMQ 1024
#define NLAYERS 4
#define BATCH 4096
#define NOUT 16

#define GM 4096
#define GN 2048
#define GK 1024

using f32x4 = __attribute__((ext_vector_type(4))) float;
using s16x8 = __attribute__((ext_vector_type(8))) short;

__device__ __forceinline__ float bf2f(unsigned short u) {
  union { unsigned int i; float f; } v; v.i = ((unsigned int)u) << 16; return v.f;
}
__device__ __forceinline__ unsigned short f2bf(float f) {
  union { float f; unsigned int i; } v; v.f = f;
  unsigned int x = v.i;
  return (unsigned short)((x + 0x7fffu + ((x >> 16) & 1u)) >> 16);  // RNE, finite inputs
}

// ------------------------------------------------- normalize + gate prep ---
// Block 0 lanes 0..39 additionally compute the 40 rotation gates' 8 real
// coefficients into Gg (global scratch); build_u reads them wave-uniformly.
__global__ __launch_bounds__(256) void normalize_rows(const float* __restrict__ X,
                                                      unsigned short* __restrict__ Xn,
                                                      const float* __restrict__ wts,
                                                      float* __restrict__ Gg) {
  if (blockIdx.x == 0 && threadIdx.x < NLAYERS * NQ) {
    int g = threadIdx.x;
    float phi = wts[g * 3 + 0], th = wts[g * 3 + 1], om = wts[g * 3 + 2];
    float ct = cosf(0.5f * th), s = sinf(0.5f * th);
    float ap = 0.5f * (phi + om), am = 0.5f * (phi - om);
    float cp = cosf(ap), spp = sinf(ap), cm = cosf(am), sm = sinf(am);
    Gg[g * 8 + 0] = ct * cp;  Gg[g * 8 + 1] = -ct * spp;  // a = e^{-i(phi+om)/2} c
    Gg[g * 8 + 2] = -s * cm;  Gg[g * 8 + 3] = -s * sm;    // b = -e^{+i(phi-om)/2} s
    Gg[g * 8 + 4] = s * cm;   Gg[g * 8 + 5] = -s * sm;    // c = e^{-i(phi-om)/2} s
    Gg[g * 8 + 6] = ct * cp;  Gg[g * 8 + 7] = ct * spp;   // d = e^{+i(phi+om)/2} c
  }
  int lane = threadIdx.x & 63;
  int row = blockIdx.x * 4 + (threadIdx.x >> 6);
  const float* xr = X + (size_t)row * DIMQ;
  float4 v[4];
  float ss = 0.f;
  #pragma unroll
  for (int ii = 0; ii < 4; ++ii) {
    v[ii] = *(const float4*)(xr + ii * 256 + lane * 4);
    ss += v[ii].x*v[ii].x + v[ii].y*v[ii].y + v[ii].z*v[ii].z + v[ii].w*v[ii].w;
  }
  #pragma unroll
  for (int off = 32; off > 0; off >>= 1) ss += __shfl_xor(ss, off, 64);
  float rn = rsqrtf(ss);
  #pragma unroll
  for (int ii = 0; ii < 4; ++ii) {
    ushort4 o;
    o.x = f2bf(v[ii].x * rn); o.y = f2bf(v[ii].y * rn);
    o.z = f2bf(v[ii].z * rn); o.w = f2bf(v[ii].w * rn);
    *(ushort4*)(Xn + (size_t)row * DIMQ + ii * 256 + lane * 4) = o;
  }
}

// ---------------------------------------------------------------- build U ---
// One WAVE per basis column c. 1024 complex amplitudes live in registers:
// state index i = (lane<<4)|e  (lane = bits 9:4, e = bits 3:0),
// sR[e]/sI[e] = 32 VGPRs. No LDS, no barriers.
//  - rotation on bit p<4 : in-register 2x2 complex rotate over e-pairs
//  - rotation on bit p>=4: shfl_xor partner + per-lane (a,b)/(d,c) coef select
//  - CNOT: 4 cases (register swap / cndmask / shfl_xor / shfl+cndmask)
__global__ __launch_bounds__(256) void build_u(const float* __restrict__ Gg,
                                               unsigned short* __restrict__ Ub) {
  const int lane = threadIdx.x & 63;
  const int wid = threadIdx.x >> 6;
  const int c = blockIdx.x * 4 + wid;

  float sR[16], sI[16];
  const int claneEq = (lane == (c >> 4));
  #pragma unroll
  for (int e = 0; e < 16; ++e) {
    sR[e] = (claneEq && (e == (c & 15))) ? 1.f : 0.f;
    sI[e] = 0.f;
  }

  #pragma unroll
  for (int l = 0; l < NLAYERS; ++l) {
    #pragma unroll
    for (int q = 0; q < NQ; ++q) {
      const float* G = Gg + (l * NQ + q) * 8;   // uniform -> scalar loads
      const float G0 = G[0], G1 = G[1], G2 = G[2], G3 = G[3];
      const float G4 = G[4], G5 = G[5], G6 = G[6], G7 = G[7];
      const int p = 9 - q;                       // qubit q <-> bit p
      if (p < 4) {
        const int mt = 1 << p;
        #pragma unroll
        for (int e0 = 0; e0 < 16; ++e0) {
          if (e0 & mt) continue;
          const int e1 = e0 | mt;
          float r0 = sR[e0], i0 = sI[e0], r1 = sR[e1], i1 = sI[e1];
          sR[e0] = G0*r0 - G1*i0 + G2*r1 - G3*i1;
          sI[e0] = G0*i0 + G1*r0 + G2*i1 + G3*r1;
          sR[e1] = G4*r0 - G5*i0 + G6*r1 - G7*i1;
          sI[e1] = G4*i0 + G5*r0 + G6*i1 + G7*r1;
        }
      } else {
        const int m = 1 << (p - 4);
        const int L = (lane >> (p - 4)) & 1;
        // L=0 lane holds i0: new = a*self + b*other ; L=1: new = d*self + c*other
        const float aR = L ? G6 : G0, aI = L ? G7 : G1;
        const float bR = L ? G4 : G2, bI = L ? G5 : G3;
        #pragma unroll
        for (int e = 0; e < 16; ++e) {
          float oR = __shfl_xor(sR[e], m, 64);
          float oI = __shfl_xor(sI[e], m, 64);
          float r = sR[e], i = sI[e];
          sR[e] = aR*r - aI*i + bR*oR - bI*oI;
          sI[e] = aR*i + aI*r + bR*oI + bI*oR;
        }
      }
    }
    // CNOT layer: q=0..9, control q, target (q+r)%10; bit p = 9-q
    const int r = l % (NQ - 1) + 1;
    #pragma unroll
    for (int q = 0; q < NQ; ++q) {
      const int pc = 9 - q, pt = 9 - ((q + r) % NQ);
      if (pc < 4 && pt < 4) {
        // compile-time register swap: e with bit pc=1 swaps with e^(1<<pt)
        #pragma unroll
        for (int e = 0; e < 16; ++e) {
          if (((e >> pc) & 1) && !((e >> pt) & 1)) {
            const int e2 = e | (1 << pt);
            float tr = sR[e]; sR[e] = sR[e2]; sR[e2] = tr;
            float ti = sI[e]; sI[e] = sI[e2]; sI[e2] = ti;
          }
        }
      } else if (pc >= 4 && pt < 4) {
        const int ctl = (lane >> (pc - 4)) & 1;
        #pragma unroll
        for (int e0 = 0; e0 < 16; ++e0) {
          if (e0 & (1 << pt)) continue;
          const int e1 = e0 | (1 << pt);
          float r0 = sR[e0], i0 = sI[e0], r1 = sR[e1], i1 = sI[e1];
          sR[e0] = ctl ? r1 : r0;  sI[e0] = ctl ? i1 : i0;
          sR[e1] = ctl ? r0 : r1;  sI[e1] = ctl ? i0 : i1;
        }
      } else if (pc < 4 && pt >= 4) {
        const int m = 1 << (pt - 4);
        #pragma unroll
        for (int e = 0; e < 16; ++e) {
          if ((e >> pc) & 1) {
            sR[e] = __shfl_xor(sR[e], m, 64);
            sI[e] = __shfl_xor(sI[e], m, 64);
          }
        }
      } else {
        const int m = 1 << (pt - 4);
        const int ctl = (lane >> (pc - 4)) & 1;
        #pragma unroll
        for (int e = 0; e < 16; ++e) {
          float oR = __shfl_xor(sR[e], m, 64);
          float oI = __shfl_xor(sI[e], m, 64);
          sR[e] = ctl ? oR : sR[e];
          sI[e] = ctl ? oI : sI[e];
        }
      }
    }
  }

  // write column c of Ub (interleaved re/im rows, [2048][1024] bf16)
  unsigned short* col = Ub + c;
  #pragma unroll
  for (int e = 0; e < 16; ++e) {
    const int i = (lane << 4) | e;
    col[(size_t)(2 * i)     * DIMQ] = f2bf(sR[e]);
    col[(size_t)(2 * i + 1) * DIMQ] = f2bf(sI[e]);
  }
}

// ------------------------------------------------------------------ GEMM ---
__device__ __forceinline__ void gload_lds16(const void* g, void* lds) {
  __builtin_amdgcn_global_load_lds(
      (const __attribute__((address_space(1))) unsigned int*)g,
      (__attribute__((address_space(3))) unsigned int*)lds, 16, 0, 0);
}

// C[b,j] = sum_k A[b,k]*B[j,k]; A=Xn (4096x1024 bf16), B=Ub (2048x1024 bf16),
// C=Y bf16. 128x128 tile, BK=64, 4 waves of 64x64, 16x16x32 MFMA.
// XOR chunk swizzle: LDS chunk (row,ch) holds global chunk ch^(row&7) so
// fragment ds_read_b128s spread over all 32 banks (2 lanes/bank = free).
__global__ __launch_bounds__(256) void gemm_bt(const unsigned short* __restrict__ A,
                                               const unsigned short* __restrict__ B,
                                               unsigned short* __restrict__ C) {
  __shared__ char lds[32768];
  char* As = lds;
  char* Bs = lds + 16384;
  int tid = threadIdx.x;
  int lane = tid & 63;
  int w = tid >> 6;
  int mtile = blockIdx.x & 31;
  int ntile = blockIdx.x >> 5;
  int wm = (w & 1) * 64;
  int wn = (w >> 1) * 64;
  const unsigned short* Ag = A + (size_t)mtile * 128 * GK;
  const unsigned short* Bg = B + (size_t)ntile * 128 * GK;
  f32x4 acc[4][4];
  #pragma unroll
  for (int i = 0; i < 4; ++i)
    #pragma unroll
    for (int j = 0; j < 4; ++j) acc[i][j] = (f32x4){0.f, 0.f, 0.f, 0.f};

  for (int kt = 0; kt < GK; kt += 64) {
    __syncthreads();
    #pragma unroll
    for (int s = 0; s < 4; ++s) {
      int chunk = (w << 8) | (s << 6) | lane;   // 0..1023 over the 4 waves
      int row = chunk >> 3, ch = chunk & 7;
      int sch = ch ^ (row & 7);                 // which global chunk lands here
      gload_lds16(Ag + (size_t)row * GK + kt + sch * 8, As + (((w << 2) + s) << 10));
      gload_lds16(Bg + (size_t)row * GK + kt + sch * 8, Bs + (((w << 2) + s) << 10));
    }
    __builtin_amdgcn_s_waitcnt(0);
    __syncthreads();
    #pragma unroll
    for (int ks = 0; ks < 2; ++ks) {
      s16x8 af[4], bfr[4];
      #pragma unroll
      for (int mt = 0; mt < 4; ++mt) {
        int rowa = wm + mt * 16 + (lane & 15);
        int kc = (ks << 2) + (lane >> 4);
        af[mt] = *(const s16x8*)(As + (((rowa << 3) + (kc ^ (rowa & 7))) << 4));
        int rowb = wn + mt * 16 + (lane & 15);
        bfr[mt] = *(const s16x8*)(Bs + (((rowb << 3) + (kc ^ (rowb & 7))) << 4));
      }
      #pragma unroll
      for (int mt = 0; mt < 4; ++mt)
        #pragma unroll
        for (int nt = 0; nt < 4; ++nt)
          acc[mt][nt] = __builtin_amdgcn_mfma_f32_16x16x32_bf16(af[mt], bfr[nt],
                                                                acc[mt][nt], 0, 0, 0);
    }
  }
  int quad = lane >> 4, cn = lane & 15;
  #pragma unroll
  for (int mt = 0; mt < 4; ++mt)
    #pragma unroll
    for (int nt = 0; nt < 4; ++nt)
      #pragma unroll
      for (int r = 0; r < 4; ++r) {
        int gm = mtile * 128 + wm + mt * 16 + quad * 4 + r;
        int gn = ntile * 128 + wn + nt * 16 + cn;
        C[(size_t)gm * GN + gn] = f2bf(acc[mt][nt][r]);
      }
}

// ---------------------------------------------------------------- reduce ---
// out[b,o] = bias[o] + sum_q z_q W[o,q];  z_q = sum_i sign(i,q)*(yr^2+yi^2)
__global__ __launch_bounds__(256) void reduce_out(const unsigned short* __restrict__ Y,
                                                  const float* __restrict__ W,
                                                  const float* __restrict__ bias,
                                                  float* __restrict__ out) {
  int lane = threadIdx.x & 63;
  int row = blockIdx.x * 4 + (threadIdx.x >> 6);
  const unsigned short* yr = Y + (size_t)row * 2048;
  float z[10];
  #pragma unroll
  for (int q = 0; q < 10; ++q) z[q] = 0.f;
  #pragma unroll
  for (int ii = 0; ii < 16; ++ii) {
    int i = ii * 64 + lane;
    ushort2 u = *(const ushort2*)(yr + 2 * i);
    float re = bf2f(u.x), im = bf2f(u.y);
    float p = re * re + im * im;
    #pragma unroll
    for (int q = 0; q < 10; ++q)
      z[q] += ((i >> (9 - q)) & 1) ? -p : p;
  }
  #pragma unroll
  for (int q = 0; q < 10; ++q)
    #pragma unroll
    for (int off = 32; off > 0; off >>= 1) z[q] += __shfl_xor(z[q], off, 64);
  if (lane < 16) {
    float acc = bias[lane];
    #pragma unroll
    for (int q = 0; q < 10; ++q) acc += z[q] * W[lane * 10 + q];
    out[(size_t)row * 16 + lane] = acc;
  }
}

extern "C" void kernel_launch(void* const* d_in, const int* in_sizes, int n_in,
                              void* d_out, int out_size, void* d_ws, size_t ws_size,
                              hipStream_t stream) {
  const float* X    = (const float*)d_in[0];
  const float* wts  = (const float*)d_in[1];
  const float* W    = (const float*)d_in[2];
  const float* bias = (const float*)d_in[3];
  float* out = (float*)d_out;
  char* ws = (char*)d_ws;
  unsigned short* Xn = (unsigned short*)ws;                       // 8 MB
  unsigned short* Ub = (unsigned short*)(ws + 8u  * 1024 * 1024); // 4 MB
  unsigned short* Y  = (unsigned short*)(ws + 12u * 1024 * 1024); // 16 MB
  float* Gg          = (float*)(ws + 28u * 1024 * 1024);          // 1.25 KB

  hipLaunchKernelGGL(normalize_rows, dim3(BATCH / 4), dim3(256), 0, stream, X, Xn, wts, Gg);
  hipLaunchKernelGGL(build_u,        dim3(DIMQ / 4),  dim3(256), 0, stream, Gg, Ub);
  hipLaunchKernelGGL(gemm_bt,        dim3((GM/128)*(GN/128)), dim3(256), 0, stream, Xn, Ub, Y);
  hipLaunchKernelGGL(reduce_out,     dim3(BATCH / 4), dim3(256), 0, stream, Y, W, bias, out);
}

// Round 4
// 140.807 us; speedup vs baseline: 1.0516x; 1.0516x over previous
//
#include <hip/hip_runtime.h>
#include <hip/hip_bf16.h>
#include <stdint.h>

#define NQ 10
#define DIMQ 1024
#define NLAYERS 4
#define BATCH 4096
#define NOUT 16

#define GM 4096
#define GN 2048
#define GK 1024

using f32x4 = __attribute__((ext_vector_type(4))) float;
using s16x8 = __attribute__((ext_vector_type(8))) short;

__device__ __forceinline__ float bf2f(unsigned short u) {
  union { unsigned int i; float f; } v; v.i = ((unsigned int)u) << 16; return v.f;
}
__device__ __forceinline__ unsigned short f2bf(float f) {
  union { float f; unsigned int i; } v; v.f = f;
  unsigned int x = v.i;
  return (unsigned short)((x + 0x7fffu + ((x >> 16) & 1u)) >> 16);  // RNE, finite inputs
}

// ------------------------------------------------- normalize + gate prep ---
__global__ __launch_bounds__(256) void normalize_rows(const float* __restrict__ X,
                                                      unsigned short* __restrict__ Xn,
                                                      const float* __restrict__ wts,
                                                      float* __restrict__ Gg) {
  if (blockIdx.x == 0 && threadIdx.x < NLAYERS * NQ) {
    int g = threadIdx.x;
    float phi = wts[g * 3 + 0], th = wts[g * 3 + 1], om = wts[g * 3 + 2];
    float ct = cosf(0.5f * th), s = sinf(0.5f * th);
    float ap = 0.5f * (phi + om), am = 0.5f * (phi - om);
    float cp = cosf(ap), spp = sinf(ap), cm = cosf(am), sm = sinf(am);
    Gg[g * 8 + 0] = ct * cp;  Gg[g * 8 + 1] = -ct * spp;  // a = e^{-i(phi+om)/2} c
    Gg[g * 8 + 2] = -s * cm;  Gg[g * 8 + 3] = -s * sm;    // b = -e^{+i(phi-om)/2} s
    Gg[g * 8 + 4] = s * cm;   Gg[g * 8 + 5] = -s * sm;    // c = e^{-i(phi-om)/2} s
    Gg[g * 8 + 6] = ct * cp;  Gg[g * 8 + 7] = ct * spp;   // d = e^{+i(phi+om)/2} c
  }
  int lane = threadIdx.x & 63;
  int row = blockIdx.x * 4 + (threadIdx.x >> 6);
  const float* xr = X + (size_t)row * DIMQ;
  float4 v[4];
  float ss = 0.f;
  #pragma unroll
  for (int ii = 0; ii < 4; ++ii) {
    v[ii] = *(const float4*)(xr + ii * 256 + lane * 4);
    ss += v[ii].x*v[ii].x + v[ii].y*v[ii].y + v[ii].z*v[ii].z + v[ii].w*v[ii].w;
  }
  #pragma unroll
  for (int off = 32; off > 0; off >>= 1) ss += __shfl_xor(ss, off, 64);
  float rn = rsqrtf(ss);
  #pragma unroll
  for (int ii = 0; ii < 4; ++ii) {
    ushort4 o;
    o.x = f2bf(v[ii].x * rn); o.y = f2bf(v[ii].y * rn);
    o.z = f2bf(v[ii].z * rn); o.w = f2bf(v[ii].w * rn);
    *(ushort4*)(Xn + (size_t)row * DIMQ + ii * 256 + lane * 4) = o;
  }
}

// ---------------------------------------------------------------- build U ---
// One WAVE per basis column c; 1024 amplitudes in registers
// (i = (lane<<4)|e). No LDS, no barriers. Output written COALESCED as
// packed (R,I) u32 rows Ut[c][i] (4 KB contiguous per wave); transpose_u
// converts to the GEMM B^T layout. (R3 post-mortem: the strided 2B column
// stores — 64 lines per store inst — were the 51 us, not the gate math.)
__global__ __launch_bounds__(256) void build_u(const float* __restrict__ Gg,
                                               unsigned int* __restrict__ Ut) {
  const int lane = threadIdx.x & 63;
  const int wid = threadIdx.x >> 6;
  const int c = blockIdx.x * 4 + wid;

  float sR[16], sI[16];
  const int claneEq = (lane == (c >> 4));
  #pragma unroll
  for (int e = 0; e < 16; ++e) {
    sR[e] = (claneEq && (e == (c & 15))) ? 1.f : 0.f;
    sI[e] = 0.f;
  }

  #pragma unroll
  for (int l = 0; l < NLAYERS; ++l) {
    #pragma unroll
    for (int q = 0; q < NQ; ++q) {
      const float* G = Gg + (l * NQ + q) * 8;   // uniform -> scalar loads
      const float G0 = G[0], G1 = G[1], G2 = G[2], G3 = G[3];
      const float G4 = G[4], G5 = G[5], G6 = G[6], G7 = G[7];
      const int p = 9 - q;                       // qubit q <-> bit p
      if (p < 4) {
        const int mt = 1 << p;
        #pragma unroll
        for (int e0 = 0; e0 < 16; ++e0) {
          if (e0 & mt) continue;
          const int e1 = e0 | mt;
          float r0 = sR[e0], i0 = sI[e0], r1 = sR[e1], i1 = sI[e1];
          sR[e0] = G0*r0 - G1*i0 + G2*r1 - G3*i1;
          sI[e0] = G0*i0 + G1*r0 + G2*i1 + G3*r1;
          sR[e1] = G4*r0 - G5*i0 + G6*r1 - G7*i1;
          sI[e1] = G4*i0 + G5*r0 + G6*i1 + G7*r1;
        }
      } else {
        const int m = 1 << (p - 4);
        const int L = (lane >> (p - 4)) & 1;
        const float aR = L ? G6 : G0, aI = L ? G7 : G1;
        const float bR = L ? G4 : G2, bI = L ? G5 : G3;
        #pragma unroll
        for (int e = 0; e < 16; ++e) {
          float oR = __shfl_xor(sR[e], m, 64);
          float oI = __shfl_xor(sI[e], m, 64);
          float r = sR[e], i = sI[e];
          sR[e] = aR*r - aI*i + bR*oR - bI*oI;
          sI[e] = aR*i + aI*r + bR*oI + bI*oR;
        }
      }
    }
    const int r = l % (NQ - 1) + 1;
    #pragma unroll
    for (int q = 0; q < NQ; ++q) {
      const int pc = 9 - q, pt = 9 - ((q + r) % NQ);
      if (pc < 4 && pt < 4) {
        #pragma unroll
        for (int e = 0; e < 16; ++e) {
          if (((e >> pc) & 1) && !((e >> pt) & 1)) {
            const int e2 = e | (1 << pt);
            float tr = sR[e]; sR[e] = sR[e2]; sR[e2] = tr;
            float ti = sI[e]; sI[e] = sI[e2]; sI[e2] = ti;
          }
        }
      } else if (pc >= 4 && pt < 4) {
        const int ctl = (lane >> (pc - 4)) & 1;
        #pragma unroll
        for (int e0 = 0; e0 < 16; ++e0) {
          if (e0 & (1 << pt)) continue;
          const int e1 = e0 | (1 << pt);
          float r0 = sR[e0], i0 = sI[e0], r1 = sR[e1], i1 = sI[e1];
          sR[e0] = ctl ? r1 : r0;  sI[e0] = ctl ? i1 : i0;
          sR[e1] = ctl ? r0 : r1;  sI[e1] = ctl ? i0 : i1;
        }
      } else if (pc < 4 && pt >= 4) {
        const int m = 1 << (pt - 4);
        #pragma unroll
        for (int e = 0; e < 16; ++e) {
          if ((e >> pc) & 1) {
            sR[e] = __shfl_xor(sR[e], m, 64);
            sI[e] = __shfl_xor(sI[e], m, 64);
          }
        }
      } else {
        const int m = 1 << (pt - 4);
        const int ctl = (lane >> (pc - 4)) & 1;
        #pragma unroll
        for (int e = 0; e < 16; ++e) {
          float oR = __shfl_xor(sR[e], m, 64);
          float oI = __shfl_xor(sI[e], m, 64);
          sR[e] = ctl ? oR : sR[e];
          sI[e] = ctl ? oI : sI[e];
        }
      }
    }
  }

  // coalesced write: Ut[c][i] = pack(bf16(R), bf16(I)), i = (lane<<4)|e
  unsigned int* rowp = Ut + (size_t)c * 1024 + (lane << 4);
  #pragma unroll
  for (int g4 = 0; g4 < 4; ++g4) {
    uint4 o;
    o.x = (unsigned)f2bf(sR[g4*4+0]) | ((unsigned)f2bf(sI[g4*4+0]) << 16);
    o.y = (unsigned)f2bf(sR[g4*4+1]) | ((unsigned)f2bf(sI[g4*4+1]) << 16);
    o.z = (unsigned)f2bf(sR[g4*4+2]) | ((unsigned)f2bf(sI[g4*4+2]) << 16);
    o.w = (unsigned)f2bf(sR[g4*4+3]) | ((unsigned)f2bf(sI[g4*4+3]) << 16);
    *(uint4*)(rowp + g4 * 4) = o;
  }
}

// ------------------------------------------------------------- transpose ---
// Ub[2i][c] = lo16(Ut[c][i]), Ub[2i+1][c] = hi16(Ut[c][i]).
// 64 i x 64 c tiles, u32 granularity in LDS (+pad 65 -> 2 lanes/bank, free),
// coalesced global on both sides.
__global__ __launch_bounds__(256) void transpose_u(const unsigned int* __restrict__ Ut,
                                                   unsigned short* __restrict__ Ub) {
  __shared__ unsigned int T[64][65];
  const int t = threadIdx.x;
  const int I0 = (blockIdx.x & 15) * 64;
  const int C0 = (blockIdx.x >> 4) * 64;
  {
    const int cr = t >> 2, ib = (t & 3) * 16;
    const unsigned int* src = Ut + (size_t)(C0 + cr) * 1024 + I0 + ib;
    #pragma unroll
    for (int g4 = 0; g4 < 4; ++g4) {
      uint4 v = *(const uint4*)(src + g4 * 4);
      T[ib + g4*4 + 0][cr] = v.x;
      T[ib + g4*4 + 1][cr] = v.y;
      T[ib + g4*4 + 2][cr] = v.z;
      T[ib + g4*4 + 3][cr] = v.w;
    }
  }
  __syncthreads();
  {
    const int il = t >> 2, cb = (t & 3) * 16;
    union { unsigned short u16[16]; uint4 q[2]; } LO, HI;
    #pragma unroll
    for (int k = 0; k < 16; ++k) {
      unsigned int u = T[il][cb + k];
      LO.u16[k] = (unsigned short)(u & 0xffffu);
      HI.u16[k] = (unsigned short)(u >> 16);
    }
    unsigned short* d0 = Ub + (size_t)(2 * (I0 + il)) * DIMQ + C0 + cb;
    unsigned short* d1 = d0 + DIMQ;
    *(uint4*)(d0 + 0) = LO.q[0];
    *(uint4*)(d0 + 8) = LO.q[1];
    *(uint4*)(d1 + 0) = HI.q[0];
    *(uint4*)(d1 + 8) = HI.q[1];
  }
}

// ------------------------------------------------------------------ GEMM ---
__device__ __forceinline__ void gload_lds16(const void* g, void* lds) {
  __builtin_amdgcn_global_load_lds(
      (const __attribute__((address_space(1))) unsigned int*)g,
      (__attribute__((address_space(3))) unsigned int*)lds, 16, 0, 0);
}

// C[b,j] = sum_k A[b,k]*B[j,k]; A=Xn (4096x1024 bf16), B=Ub (2048x1024 bf16),
// C=Y bf16. 128x128 tile, BK=64, 4 waves of 64x64, 16x16x32 MFMA.
__global__ __launch_bounds__(256) void gemm_bt(const unsigned short* __restrict__ A,
                                               const unsigned short* __restrict__ B,
                                               unsigned short* __restrict__ C) {
  __shared__ char lds[32768];
  char* As = lds;
  char* Bs = lds + 16384;
  int tid = threadIdx.x;
  int lane = tid & 63;
  int w = tid >> 6;
  int mtile = blockIdx.x & 31;
  int ntile = blockIdx.x >> 5;
  int wm = (w & 1) * 64;
  int wn = (w >> 1) * 64;
  const unsigned short* Ag = A + (size_t)mtile * 128 * GK;
  const unsigned short* Bg = B + (size_t)ntile * 128 * GK;
  f32x4 acc[4][4];
  #pragma unroll
  for (int i = 0; i < 4; ++i)
    #pragma unroll
    for (int j = 0; j < 4; ++j) acc[i][j] = (f32x4){0.f, 0.f, 0.f, 0.f};

  for (int kt = 0; kt < GK; kt += 64) {
    __syncthreads();
    #pragma unroll
    for (int s = 0; s < 4; ++s) {
      int chunk = (w << 8) | (s << 6) | lane;
      int row = chunk >> 3, ch = chunk & 7;
      int sch = ch ^ (row & 7);
      gload_lds16(Ag + (size_t)row * GK + kt + sch * 8, As + (((w << 2) + s) << 10));
      gload_lds16(Bg + (size_t)row * GK + kt + sch * 8, Bs + (((w << 2) + s) << 10));
    }
    __builtin_amdgcn_s_waitcnt(0);
    __syncthreads();
    #pragma unroll
    for (int ks = 0; ks < 2; ++ks) {
      s16x8 af[4], bfr[4];
      #pragma unroll
      for (int mt = 0; mt < 4; ++mt) {
        int rowa = wm + mt * 16 + (lane & 15);
        int kc = (ks << 2) + (lane >> 4);
        af[mt] = *(const s16x8*)(As + (((rowa << 3) + (kc ^ (rowa & 7))) << 4));
        int rowb = wn + mt * 16 + (lane & 15);
        bfr[mt] = *(const s16x8*)(Bs + (((rowb << 3) + (kc ^ (rowb & 7))) << 4));
      }
      #pragma unroll
      for (int mt = 0; mt < 4; ++mt)
        #pragma unroll
        for (int nt = 0; nt < 4; ++nt)
          acc[mt][nt] = __builtin_amdgcn_mfma_f32_16x16x32_bf16(af[mt], bfr[nt],
                                                                acc[mt][nt], 0, 0, 0);
    }
  }
  int quad = lane >> 4, cn = lane & 15;
  #pragma unroll
  for (int mt = 0; mt < 4; ++mt)
    #pragma unroll
    for (int nt = 0; nt < 4; ++nt)
      #pragma unroll
      for (int r = 0; r < 4; ++r) {
        int gm = mtile * 128 + wm + mt * 16 + quad * 4 + r;
        int gn = ntile * 128 + wn + nt * 16 + cn;
        C[(size_t)gm * GN + gn] = f2bf(acc[mt][nt][r]);
      }
}

// ---------------------------------------------------------------- reduce ---
__global__ __launch_bounds__(256) void reduce_out(const unsigned short* __restrict__ Y,
                                                  const float* __restrict__ W,
                                                  const float* __restrict__ bias,
                                                  float* __restrict__ out) {
  int lane = threadIdx.x & 63;
  int row = blockIdx.x * 4 + (threadIdx.x >> 6);
  const unsigned short* yr = Y + (size_t)row * 2048;
  float z[10];
  #pragma unroll
  for (int q = 0; q < 10; ++q) z[q] = 0.f;
  #pragma unroll
  for (int ii = 0; ii < 16; ++ii) {
    int i = ii * 64 + lane;
    ushort2 u = *(const ushort2*)(yr + 2 * i);
    float re = bf2f(u.x), im = bf2f(u.y);
    float p = re * re + im * im;
    #pragma unroll
    for (int q = 0; q < 10; ++q)
      z[q] += ((i >> (9 - q)) & 1) ? -p : p;
  }
  #pragma unroll
  for (int q = 0; q < 10; ++q)
    #pragma unroll
    for (int off = 32; off > 0; off >>= 1) z[q] += __shfl_xor(z[q], off, 64);
  if (lane < 16) {
    float acc = bias[lane];
    #pragma unroll
    for (int q = 0; q < 10; ++q) acc += z[q] * W[lane * 10 + q];
    out[(size_t)row * 16 + lane] = acc;
  }
}

extern "C" void kernel_launch(void* const* d_in, const int* in_sizes, int n_in,
                              void* d_out, int out_size, void* d_ws, size_t ws_size,
                              hipStream_t stream) {
  const float* X    = (const float*)d_in[0];
  const float* wts  = (const float*)d_in[1];
  const float* W    = (const float*)d_in[2];
  const float* bias = (const float*)d_in[3];
  float* out = (float*)d_out;
  char* ws = (char*)d_ws;
  unsigned short* Xn = (unsigned short*)ws;                       // 8 MB
  unsigned short* Ub = (unsigned short*)(ws + 8u  * 1024 * 1024); // 4 MB
  unsigned short* Y  = (unsigned short*)(ws + 12u * 1024 * 1024); // 16 MB
  float* Gg          = (float*)(ws + 28u * 1024 * 1024);          // 1.25 KB
  unsigned int* Ut   = (unsigned int*)(ws + 32u * 1024 * 1024);   // 4 MB

  hipLaunchKernelGGL(normalize_rows, dim3(BATCH / 4), dim3(256), 0, stream, X, Xn, wts, Gg);
  hipLaunchKernelGGL(build_u,        dim3(DIMQ / 4),  dim3(256), 0, stream, Gg, Ut);
  hipLaunchKernelGGL(transpose_u,    dim3(256),       dim3(256), 0, stream, Ut, Ub);
  hipLaunchKernelGGL(gemm_bt,        dim3((GM/128)*(GN/128)), dim3(256), 0, stream, Xn, Ub, Y);
  hipLaunchKernelGGL(reduce_out,     dim3(BATCH / 4), dim3(256), 0, stream, Y, W, bias, out);
}

// Round 5
// 127.685 us; speedup vs baseline: 1.1597x; 1.1028x over previous
//
#include <hip/hip_runtime.h>
#include <hip/hip_bf16.h>
#include <stdint.h>

#define NQ 10
#define DIMQ 1024
#define NLAYERS 4
#define BATCH 4096
#define NOUT 16

#define GM 4096
#define GN 2048
#define GK 1024

using f32x4 = __attribute__((ext_vector_type(4))) float;
using s16x8 = __attribute__((ext_vector_type(8))) short;

__device__ __forceinline__ float bf2f(unsigned short u) {
  union { unsigned int i; float f; } v; v.i = ((unsigned int)u) << 16; return v.f;
}
__device__ __forceinline__ unsigned short f2bf(float f) {
  union { float f; unsigned int i; } v; v.f = f;
  unsigned int x = v.i;
  return (unsigned short)((x + 0x7fffu + ((x >> 16) & 1u)) >> 16);  // RNE, finite inputs
}

// ------------------------------------------------- normalize + gate prep ---
__global__ __launch_bounds__(256) void normalize_rows(const float* __restrict__ X,
                                                      unsigned short* __restrict__ Xn,
                                                      const float* __restrict__ wts,
                                                      float* __restrict__ Gg) {
  if (blockIdx.x == 0 && threadIdx.x < NLAYERS * NQ) {
    int g = threadIdx.x;
    float phi = wts[g * 3 + 0], th = wts[g * 3 + 1], om = wts[g * 3 + 2];
    float ct = cosf(0.5f * th), s = sinf(0.5f * th);
    float ap = 0.5f * (phi + om), am = 0.5f * (phi - om);
    float cp = cosf(ap), spp = sinf(ap), cm = cosf(am), sm = sinf(am);
    Gg[g * 8 + 0] = ct * cp;  Gg[g * 8 + 1] = -ct * spp;  // a = e^{-i(phi+om)/2} c
    Gg[g * 8 + 2] = -s * cm;  Gg[g * 8 + 3] = -s * sm;    // b = -e^{+i(phi-om)/2} s
    Gg[g * 8 + 4] = s * cm;   Gg[g * 8 + 5] = -s * sm;    // c = e^{-i(phi-om)/2} s
    Gg[g * 8 + 6] = ct * cp;  Gg[g * 8 + 7] = ct * spp;   // d = e^{+i(phi+om)/2} c
  }
  int lane = threadIdx.x & 63;
  int row = blockIdx.x * 4 + (threadIdx.x >> 6);
  const float* xr = X + (size_t)row * DIMQ;
  float4 v[4];
  float ss = 0.f;
  #pragma unroll
  for (int ii = 0; ii < 4; ++ii) {
    v[ii] = *(const float4*)(xr + ii * 256 + lane * 4);
    ss += v[ii].x*v[ii].x + v[ii].y*v[ii].y + v[ii].z*v[ii].z + v[ii].w*v[ii].w;
  }
  #pragma unroll
  for (int off = 32; off > 0; off >>= 1) ss += __shfl_xor(ss, off, 64);
  float rn = rsqrtf(ss);
  #pragma unroll
  for (int ii = 0; ii < 4; ++ii) {
    ushort4 o;
    o.x = f2bf(v[ii].x * rn); o.y = f2bf(v[ii].y * rn);
    o.z = f2bf(v[ii].z * rn); o.w = f2bf(v[ii].w * rn);
    *(ushort4*)(Xn + (size_t)row * DIMQ + ii * 256 + lane * 4) = o;
  }
}

// ---------------------------------------------------------------- build U ---
// TWO waves per column (R4 post-mortem: 1024 waves = 1 wave/SIMD = zero
// latency hiding; VALUBusy 25%). Wave h in {0,1} holds indices with
// bit9 = h; lane = bits 8:3, regs e = bits 2:0 (8 complex = 16 VGPR).
// 2048 waves -> 2 waves/SIMD. Bit-9 gates (p=9 rotation + pt=9 CNOT:
// 2 per layer, 8 total) exchange half-states via double-buffered LDS
// (80 B padded lane stride). All other gates in-register / shfl.
__global__ __launch_bounds__(256) void build_u(const float* __restrict__ Gg,
                                               unsigned int* __restrict__ Ut) {
  __shared__ float buf[2][4][64][20];   // [evbuf][wave][lane][16 used + 4 pad]
  const int lane = threadIdx.x & 63;
  const int w = threadIdx.x >> 6;
  const int h = w & 1;
  const int c = blockIdx.x * 2 + (w >> 1);

  float sR[8], sI[8], pR[8], pI[8];
  #pragma unroll
  for (int e = 0; e < 8; ++e) {
    sR[e] = (h == (c >> 9) && lane == ((c >> 3) & 63) && e == (c & 7)) ? 1.f : 0.f;
    sI[e] = 0.f;
  }
  int ev = 0;
  auto exchange = [&]() {
    float* wp = &buf[ev & 1][w][lane][0];
    #pragma unroll
    for (int g = 0; g < 4; ++g)
      *(float4*)(wp + 4 * g) = make_float4(sR[2*g], sI[2*g], sR[2*g+1], sI[2*g+1]);
    __syncthreads();
    const float* rp = &buf[ev & 1][w ^ 1][lane][0];
    #pragma unroll
    for (int g = 0; g < 4; ++g) {
      float4 t = *(const float4*)(rp + 4 * g);
      pR[2*g] = t.x; pI[2*g] = t.y; pR[2*g+1] = t.z; pI[2*g+1] = t.w;
    }
    ++ev;
  };

  #pragma unroll
  for (int l = 0; l < NLAYERS; ++l) {
    #pragma unroll
    for (int q = 0; q < NQ; ++q) {
      const float* G = Gg + (l * NQ + q) * 8;   // uniform -> scalar loads
      const float G0 = G[0], G1 = G[1], G2 = G[2], G3 = G[3];
      const float G4 = G[4], G5 = G[5], G6 = G[6], G7 = G[7];
      const int p = 9 - q;                       // qubit q <-> bit p
      if (p < 3) {                               // reg bit
        const int mt = 1 << p;
        #pragma unroll
        for (int e0 = 0; e0 < 8; ++e0) {
          if (e0 & mt) continue;
          const int e1 = e0 | mt;
          float r0 = sR[e0], i0 = sI[e0], r1 = sR[e1], i1 = sI[e1];
          sR[e0] = G0*r0 - G1*i0 + G2*r1 - G3*i1;
          sI[e0] = G0*i0 + G1*r0 + G2*i1 + G3*r1;
          sR[e1] = G4*r0 - G5*i0 + G6*r1 - G7*i1;
          sI[e1] = G4*i0 + G5*r0 + G6*i1 + G7*r1;
        }
      } else if (p < 9) {                        // lane bit
        const int m = 1 << (p - 3);
        const int L = (lane >> (p - 3)) & 1;
        const float aR = L ? G6 : G0, aI = L ? G7 : G1;
        const float bR = L ? G4 : G2, bI = L ? G5 : G3;
        #pragma unroll
        for (int e = 0; e < 8; ++e) {
          float oR = __shfl_xor(sR[e], m, 64);
          float oI = __shfl_xor(sI[e], m, 64);
          float r = sR[e], i = sI[e];
          sR[e] = aR*r - aI*i + bR*oR - bI*oI;
          sI[e] = aR*i + aI*r + bR*oI + bI*oR;
        }
      } else {                                   // wave bit (p==9)
        exchange();
        const float aR = h ? G6 : G0, aI = h ? G7 : G1;
        const float bR = h ? G4 : G2, bI = h ? G5 : G3;
        #pragma unroll
        for (int e = 0; e < 8; ++e) {
          float r = sR[e], i = sI[e];
          sR[e] = aR*r - aI*i + bR*pR[e] - bI*pI[e];
          sI[e] = aR*i + aI*r + bR*pI[e] + bI*pR[e];
        }
      }
    }
    const int r = l % (NQ - 1) + 1;
    #pragma unroll
    for (int q = 0; q < NQ; ++q) {
      const int pc = 9 - q, pt = 9 - ((q + r) % NQ);
      if (pt == 9) {                             // target = wave bit: exchange
        exchange();
        if (pc < 3) {
          #pragma unroll
          for (int e = 0; e < 8; ++e)
            if ((e >> pc) & 1) { sR[e] = pR[e]; sI[e] = pI[e]; }
        } else {
          const int ctl = (lane >> (pc - 3)) & 1;
          #pragma unroll
          for (int e = 0; e < 8; ++e) {
            sR[e] = ctl ? pR[e] : sR[e];
            sI[e] = ctl ? pI[e] : sI[e];
          }
        }
      } else if (pc == 9) {                      // control = wave bit (uniform)
        if (pt < 3) {
          if (h) {
            #pragma unroll
            for (int e = 0; e < 8; ++e)
              if (((e >> pt) & 1) == 0) {
                const int e2 = e | (1 << pt);
                float tr = sR[e]; sR[e] = sR[e2]; sR[e2] = tr;
                float ti = sI[e]; sI[e] = sI[e2]; sI[e2] = ti;
              }
          }
        } else {
          const int m = 1 << (pt - 3);
          #pragma unroll
          for (int e = 0; e < 8; ++e) {
            float oR = __shfl_xor(sR[e], m, 64);
            float oI = __shfl_xor(sI[e], m, 64);
            if (h) { sR[e] = oR; sI[e] = oI; }
          }
        }
      } else if (pc < 3 && pt < 3) {
        #pragma unroll
        for (int e = 0; e < 8; ++e)
          if (((e >> pc) & 1) && !((e >> pt) & 1)) {
            const int e2 = e | (1 << pt);
            float tr = sR[e]; sR[e] = sR[e2]; sR[e2] = tr;
            float ti = sI[e]; sI[e] = sI[e2]; sI[e2] = ti;
          }
      } else if (pc >= 3 && pt < 3) {
        const int ctl = (lane >> (pc - 3)) & 1;
        #pragma unroll
        for (int e0 = 0; e0 < 8; ++e0) {
          if (e0 & (1 << pt)) continue;
          const int e1 = e0 | (1 << pt);
          float r0 = sR[e0], i0 = sI[e0], r1 = sR[e1], i1 = sI[e1];
          sR[e0] = ctl ? r1 : r0;  sI[e0] = ctl ? i1 : i0;
          sR[e1] = ctl ? r0 : r1;  sI[e1] = ctl ? i0 : i1;
        }
      } else if (pc < 3 && pt >= 3) {
        const int m = 1 << (pt - 3);
        #pragma unroll
        for (int e = 0; e < 8; ++e)
          if ((e >> pc) & 1) {
            sR[e] = __shfl_xor(sR[e], m, 64);
            sI[e] = __shfl_xor(sI[e], m, 64);
          }
      } else {                                   // both lane bits
        const int m = 1 << (pt - 3);
        const int ctl = (lane >> (pc - 3)) & 1;
        #pragma unroll
        for (int e = 0; e < 8; ++e) {
          float oR = __shfl_xor(sR[e], m, 64);
          float oI = __shfl_xor(sI[e], m, 64);
          sR[e] = ctl ? oR : sR[e];
          sI[e] = ctl ? oI : sI[e];
        }
      }
    }
  }

  // coalesced: Ut[c][i] = pack(bf16 R, bf16 I), i = (h<<9)|(lane<<3)|e
  unsigned int* rowp = Ut + (size_t)c * 1024 + (h << 9) + (lane << 3);
  #pragma unroll
  for (int g4 = 0; g4 < 2; ++g4) {
    uint4 o;
    o.x = (unsigned)f2bf(sR[g4*4+0]) | ((unsigned)f2bf(sI[g4*4+0]) << 16);
    o.y = (unsigned)f2bf(sR[g4*4+1]) | ((unsigned)f2bf(sI[g4*4+1]) << 16);
    o.z = (unsigned)f2bf(sR[g4*4+2]) | ((unsigned)f2bf(sI[g4*4+2]) << 16);
    o.w = (unsigned)f2bf(sR[g4*4+3]) | ((unsigned)f2bf(sI[g4*4+3]) << 16);
    *(uint4*)(rowp + g4 * 4) = o;
  }
}

// ------------------------------------------------------------- transpose ---
__global__ __launch_bounds__(256) void transpose_u(const unsigned int* __restrict__ Ut,
                                                   unsigned short* __restrict__ Ub) {
  __shared__ unsigned int T[64][65];
  const int t = threadIdx.x;
  const int I0 = (blockIdx.x & 15) * 64;
  const int C0 = (blockIdx.x >> 4) * 64;
  {
    const int cr = t >> 2, ib = (t & 3) * 16;
    const unsigned int* src = Ut + (size_t)(C0 + cr) * 1024 + I0 + ib;
    #pragma unroll
    for (int g4 = 0; g4 < 4; ++g4) {
      uint4 v = *(const uint4*)(src + g4 * 4);
      T[ib + g4*4 + 0][cr] = v.x;
      T[ib + g4*4 + 1][cr] = v.y;
      T[ib + g4*4 + 2][cr] = v.z;
      T[ib + g4*4 + 3][cr] = v.w;
    }
  }
  __syncthreads();
  {
    const int il = t >> 2, cb = (t & 3) * 16;
    union { unsigned short u16[16]; uint4 q[2]; } LO, HI;
    #pragma unroll
    for (int k = 0; k < 16; ++k) {
      unsigned int u = T[il][cb + k];
      LO.u16[k] = (unsigned short)(u & 0xffffu);
      HI.u16[k] = (unsigned short)(u >> 16);
    }
    unsigned short* d0 = Ub + (size_t)(2 * (I0 + il)) * DIMQ + C0 + cb;
    unsigned short* d1 = d0 + DIMQ;
    *(uint4*)(d0 + 0) = LO.q[0];
    *(uint4*)(d0 + 8) = LO.q[1];
    *(uint4*)(d1 + 0) = HI.q[0];
    *(uint4*)(d1 + 8) = HI.q[1];
  }
}

// ------------------------------------------------------------------ GEMM ---
__device__ __forceinline__ void gload_lds16(const void* g, void* lds) {
  __builtin_amdgcn_global_load_lds(
      (const __attribute__((address_space(1))) unsigned int*)g,
      (__attribute__((address_space(3))) unsigned int*)lds, 16, 0, 0);
}

__global__ __launch_bounds__(256) void gemm_bt(const unsigned short* __restrict__ A,
                                               const unsigned short* __restrict__ B,
                                               unsigned short* __restrict__ C) {
  __shared__ char lds[32768];
  char* As = lds;
  char* Bs = lds + 16384;
  int tid = threadIdx.x;
  int lane = tid & 63;
  int w = tid >> 6;
  int mtile = blockIdx.x & 31;
  int ntile = blockIdx.x >> 5;
  int wm = (w & 1) * 64;
  int wn = (w >> 1) * 64;
  const unsigned short* Ag = A + (size_t)mtile * 128 * GK;
  const unsigned short* Bg = B + (size_t)ntile * 128 * GK;
  f32x4 acc[4][4];
  #pragma unroll
  for (int i = 0; i < 4; ++i)
    #pragma unroll
    for (int j = 0; j < 4; ++j) acc[i][j] = (f32x4){0.f, 0.f, 0.f, 0.f};

  for (int kt = 0; kt < GK; kt += 64) {
    __syncthreads();
    #pragma unroll
    for (int s = 0; s < 4; ++s) {
      int chunk = (w << 8) | (s << 6) | lane;
      int row = chunk >> 3, ch = chunk & 7;
      int sch = ch ^ (row & 7);
      gload_lds16(Ag + (size_t)row * GK + kt + sch * 8, As + (((w << 2) + s) << 10));
      gload_lds16(Bg + (size_t)row * GK + kt + sch * 8, Bs + (((w << 2) + s) << 10));
    }
    __builtin_amdgcn_s_waitcnt(0);
    __syncthreads();
    #pragma unroll
    for (int ks = 0; ks < 2; ++ks) {
      s16x8 af[4], bfr[4];
      #pragma unroll
      for (int mt = 0; mt < 4; ++mt) {
        int rowa = wm + mt * 16 + (lane & 15);
        int kc = (ks << 2) + (lane >> 4);
        af[mt] = *(const s16x8*)(As + (((rowa << 3) + (kc ^ (rowa & 7))) << 4));
        int rowb = wn + mt * 16 + (lane & 15);
        bfr[mt] = *(const s16x8*)(Bs + (((rowb << 3) + (kc ^ (rowb & 7))) << 4));
      }
      #pragma unroll
      for (int mt = 0; mt < 4; ++mt)
        #pragma unroll
        for (int nt = 0; nt < 4; ++nt)
          acc[mt][nt] = __builtin_amdgcn_mfma_f32_16x16x32_bf16(af[mt], bfr[nt],
                                                                acc[mt][nt], 0, 0, 0);
    }
  }
  int quad = lane >> 4, cn = lane & 15;
  #pragma unroll
  for (int mt = 0; mt < 4; ++mt)
    #pragma unroll
    for (int nt = 0; nt < 4; ++nt)
      #pragma unroll
      for (int r = 0; r < 4; ++r) {
        int gm = mtile * 128 + wm + mt * 16 + quad * 4 + r;
        int gn = ntile * 128 + wn + nt * 16 + cn;
        C[(size_t)gm * GN + gn] = f2bf(acc[mt][nt][r]);
      }
}

// ---------------------------------------------------------------- reduce ---
__global__ __launch_bounds__(256) void reduce_out(const unsigned short* __restrict__ Y,
                                                  const float* __restrict__ W,
                                                  const float* __restrict__ bias,
                                                  float* __restrict__ out) {
  int lane = threadIdx.x & 63;
  int row = blockIdx.x * 4 + (threadIdx.x >> 6);
  const unsigned short* yr = Y + (size_t)row * 2048;
  float z[10];
  #pragma unroll
  for (int q = 0; q < 10; ++q) z[q] = 0.f;
  #pragma unroll
  for (int ii = 0; ii < 16; ++ii) {
    int i = ii * 64 + lane;
    ushort2 u = *(const ushort2*)(yr + 2 * i);
    float re = bf2f(u.x), im = bf2f(u.y);
    float p = re * re + im * im;
    #pragma unroll
    for (int q = 0; q < 10; ++q)
      z[q] += ((i >> (9 - q)) & 1) ? -p : p;
  }
  #pragma unroll
  for (int q = 0; q < 10; ++q)
    #pragma unroll
    for (int off = 32; off > 0; off >>= 1) z[q] += __shfl_xor(z[q], off, 64);
  if (lane < 16) {
    float acc = bias[lane];
    #pragma unroll
    for (int q = 0; q < 10; ++q) acc += z[q] * W[lane * 10 + q];
    out[(size_t)row * 16 + lane] = acc;
  }
}

extern "C" void kernel_launch(void* const* d_in, const int* in_sizes, int n_in,
                              void* d_out, int out_size, void* d_ws, size_t ws_size,
                              hipStream_t stream) {
  const float* X    = (const float*)d_in[0];
  const float* wts  = (const float*)d_in[1];
  const float* W    = (const float*)d_in[2];
  const float* bias = (const float*)d_in[3];
  float* out = (float*)d_out;
  char* ws = (char*)d_ws;
  unsigned short* Xn = (unsigned short*)ws;                       // 8 MB
  unsigned short* Ub = (unsigned short*)(ws + 8u  * 1024 * 1024); // 4 MB
  unsigned short* Y  = (unsigned short*)(ws + 12u * 1024 * 1024); // 16 MB
  float* Gg          = (float*)(ws + 28u * 1024 * 1024);          // 1.25 KB
  unsigned int* Ut   = (unsigned int*)(ws + 32u * 1024 * 1024);   // 4 MB

  hipLaunchKernelGGL(normalize_rows, dim3(BATCH / 4), dim3(256), 0, stream, X, Xn, wts, Gg);
  hipLaunchKernelGGL(build_u,        dim3(DIMQ / 2),  dim3(256), 0, stream, Gg, Ut);
  hipLaunchKernelGGL(transpose_u,    dim3(256),       dim3(256), 0, stream, Ut, Ub);
  hipLaunchKernelGGL(gemm_bt,        dim3((GM/128)*(GN/128)), dim3(256), 0, stream, Xn, Ub, Y);
  hipLaunchKernelGGL(reduce_out,     dim3(BATCH / 4), dim3(256), 0, stream, Y, W, bias, out);
}